// Round 14
// baseline (280.050 us; speedup 1.0000x reference)
//
#include <hip/hip_runtime.h>

#define V_   3
#define N_   200000
#define D_   128
#define B_   32768
#define K_   10
#define TOT_ 65536

constexpr int BLOCKS_PER_TERM = 512;
constexpr int ROWS_PER_BLOCK  = B_ / BLOCKS_PER_TERM;             // 64
constexpr int WAVES_PER_BLOCK = 4;                                // 256 threads
constexpr int ROWS_PER_WAVE   = ROWS_PER_BLOCK / WAVES_PER_BLOCK; // 16
constexpr int GROUPS_PER_WAVE = 4;                                // 16 lanes/row
constexpr int ITERS           = ROWS_PER_WAVE / GROUPS_PER_WAVE;  // 4

constexpr size_t TBL_ELEMS     = (size_t)V_ * N_ * D_;    // 76.8e6 per table
constexpr size_t FP8_TBL_BYTES = TBL_ELEMS;               // 76.8 MB per table
constexpr size_t ACC_BYTES     = 256;
constexpr size_t WS_NEED       = ACC_BYTES + 2 * FP8_TBL_BYTES;

// cvt geometry: one table per launch; 19.2M float4 items; block-tile-contiguous
// with 8 items/thread: 9375 blocks * 256 thr * 8 = 19,200,000 exact.
constexpr int CVT_BLOCKS = 9375;
constexpr int CVT_DEPTH  = 8;
constexpr int CVT_TILE   = 256 * CVT_DEPTH;

// Term schedule grouped by negative-sample table slice.
__device__ const int TMAP[15][3] = {
    {0, 0, 0}, {2, 1, 0}, {2, 2, 0},
    {0, 1, 1}, {2, 0, 1}, {2, 2, 1},
    {0, 2, 2}, {2, 0, 2}, {2, 1, 2},
    {1, 1, 0}, {1, 2, 0},
    {1, 0, 1}, {1, 2, 1},
    {1, 0, 2}, {1, 1, 2},
};

typedef float v2f __attribute__((ext_vector_type(2)));
typedef float v4f __attribute__((ext_vector_type(4)));

template <int CTRL>
__device__ __forceinline__ float dpp_add(float v) {
    int x = __builtin_amdgcn_update_dpp(0, __float_as_int(v), CTRL, 0xF, 0xF, true);
    return v + __int_as_float(x);
}

// 16-lane sum on the VALU pipe.
__device__ __forceinline__ float grp_sum16(float v) {
    v = dpp_add<0xB1>(v);
    v = dpp_add<0x4E>(v);
    v = dpp_add<0x124>(v);
    v = dpp_add<0x128>(v);
    return v;
}

__device__ __forceinline__ float log_sigmoid(float x) {
    float ax = fabsf(x);
    return fminf(x, 0.f) - __logf(1.f + __expf(-ax));
}

// ---------------- fp8 e4m3 helpers (HW cvt; selectors constant) ----------------
__device__ __forceinline__ unsigned cvt4_fp8(float a, float b, float c, float d) {
    int v = __builtin_amdgcn_cvt_pk_fp8_f32(a, b, 0, false);
    v = __builtin_amdgcn_cvt_pk_fp8_f32(c, d, v, true);
    return (unsigned)v;
}
template <bool HI>
__device__ __forceinline__ v2f upk2(unsigned v) {
    return __builtin_amdgcn_cvt_pk_f32_fp8((int)v, HI);
}

// Per-table conversion. Plain (cacheable) loads — NT removed: L3 retention of
// the f32 stream across replays was being defeated by the nt bit (r11-13
// confound). 8-deep forced batch before sched_barrier(0); coalesced
// tile-contiguous layout; normal stores keep fp8 tables L2/L3-resident.
template <bool ZERO_ACC>
__global__ __launch_bounds__(256) void cvt_fp8_one(
    const v4f* __restrict__ src, unsigned* __restrict__ dst,
    float* __restrict__ acc)
{
    if (ZERO_ACC && blockIdx.x == 0 && threadIdx.x < 8) acc[threadIdx.x] = 0.f;
    const size_t base = (size_t)blockIdx.x * CVT_TILE + threadIdx.x;

    v4f v0, v1, v2, v3, v4, v5, v6, v7;
    v0 = src[base + 0 * 256];
    v1 = src[base + 1 * 256];
    v2 = src[base + 2 * 256];
    v3 = src[base + 3 * 256];
    v4 = src[base + 4 * 256];
    v5 = src[base + 5 * 256];
    v6 = src[base + 6 * 256];
    v7 = src[base + 7 * 256];
    __builtin_amdgcn_sched_barrier(0);

    dst[base + 0 * 256] = cvt4_fp8(v0.x, v0.y, v0.z, v0.w);
    dst[base + 1 * 256] = cvt4_fp8(v1.x, v1.y, v1.z, v1.w);
    dst[base + 2 * 256] = cvt4_fp8(v2.x, v2.y, v2.z, v2.w);
    dst[base + 3 * 256] = cvt4_fp8(v3.x, v3.y, v3.z, v3.w);
    dst[base + 4 * 256] = cvt4_fp8(v4.x, v4.y, v4.z, v4.w);
    dst[base + 5 * 256] = cvt4_fp8(v5.x, v5.y, v5.z, v5.w);
    dst[base + 6 * 256] = cvt4_fp8(v6.x, v6.y, v6.z, v6.w);
    dst[base + 7 * 256] = cvt4_fp8(v7.x, v7.y, v7.z, v7.w);
}

// dot of this lane's 8 fp8 elements against pre-decoded center (4 x v2f),
// using packed f32 math (v_pk_fma_f32).
__device__ __forceinline__ float dotv(v2f c0, v2f c1, v2f c2, v2f c3, uint2 n) {
    v2f a0 = c0 * upk2<false>(n.x);
    v2f a1 = c1 * upk2<true>(n.x);
    a0 += c2 * upk2<false>(n.y);
    a1 += c3 * upk2<true>(n.y);
    v2f a = a0 + a1;
    return a.x + a.y;
}

// ---------------- fp8 gather kernel ----------------
__global__ __launch_bounds__(256) void sgns_fp8(
    const int*   __restrict__ countp,
    const int*   __restrict__ shuffle,
    const int*   __restrict__ nodes_idx,
    const int*   __restrict__ neigh_idx,
    const int*   __restrict__ neg1,
    const int*   __restrict__ neg2,
    const int*   __restrict__ neg3,
    const uint2* __restrict__ nodeT,
    const uint2* __restrict__ neighT,
    float*       __restrict__ acc)
{
    const int slot = blockIdx.x / BLOCKS_PER_TERM;
    const int blk  = blockIdx.x % BLOCKS_PER_TERM;
    const int wave = threadIdx.x >> 6;
    const int lane = threadIdx.x & 63;
    const int grp  = lane >> 4;
    const int lw   = lane & 15;
    const int count = countp[0];

    const int type = TMAP[slot][0];
    const int i    = TMAP[slot][1];
    const int j    = TMAP[slot][2];

    const int*   negBase;
    const uint2* negTable;
    if (type == 0)      { negTable = neighT + (size_t)i * N_ * 16; negBase = neg1 + (size_t)i * B_ * K_; }
    else if (type == 1) { negTable = nodeT  + (size_t)j * N_ * 16; negBase = neg2 + (size_t)(j * V_ + i) * B_ * K_; }
    else                { negTable = neighT + (size_t)j * N_ * 16; negBase = neg3 + (size_t)(j * V_ + i) * B_ * K_; }

    float wsum = 0.f;
    const int rowbase = blk * ROWS_PER_BLOCK + wave * ROWS_PER_WAVE;

    for (int r = 0; r < ITERS; ++r) {
        const int b  = rowbase + r * GROUPS_PER_WAVE + grp;
        const int sh = shuffle[i * TOT_ + count + b];
        const int ns = nodes_idx[i * TOT_ + sh];

        uint2 c8 = nodeT[((size_t)i * N_ + ns) * 16 + lw];

        const uint2* xrow;
        if (type == 0) {
            int gs = neigh_idx[i * TOT_ + sh];
            xrow = neighT + ((size_t)i * N_ + gs) * 16;
        } else if (type == 1) {
            xrow = nodeT + ((size_t)j * N_ + ns) * 16;
        } else {
            int gs = neigh_idx[i * TOT_ + sh];
            xrow = neighT + ((size_t)j * N_ + gs) * 16;
        }
        uint2 x8 = xrow[lw];

        int myidx = (lw < K_) ? negBase[(size_t)b * K_ + lw] : 0;

        // Broadcast neg indices, then issue ALL 10 neg loads before reducing (MLP).
        uint2 nv[K_];
#pragma unroll
        for (int k = 0; k < K_; ++k) {
            int nk = __shfl(myidx, (lane & 48) | k, 64);
            nv[k] = negTable[(size_t)nk * 16 + lw];
        }

        v2f c0 = upk2<false>(c8.x), c1 = upk2<true>(c8.x);
        v2f c2 = upk2<false>(c8.y), c3 = upk2<true>(c8.y);

        float rowacc = log_sigmoid(grp_sum16(dotv(c0, c1, c2, c3, x8)));
#pragma unroll
        for (int k = 0; k < K_; ++k) {
            rowacc += log_sigmoid(-grp_sum16(dotv(c0, c1, c2, c3, nv[k])));
        }
        wsum += rowacc;
    }

    wsum += __shfl_xor(wsum, 16, 64);
    wsum += __shfl_xor(wsum, 32, 64);

    __shared__ float part[WAVES_PER_BLOCK];
    if (lane == 0) part[wave] = wsum;
    __syncthreads();
    if (threadIdx.x == 0) {
        float s = part[0] + part[1] + part[2] + part[3];
        atomicAdd(&acc[type], s);
    }
}

// ---------------- f32 fallback (proven round-3 kernel) ----------------
__device__ __forceinline__ float dot8(float4 a0, float4 a1, float4 b0, float4 b1) {
    float s = a0.x * b0.x;
    s = fmaf(a0.y, b0.y, s);
    s = fmaf(a0.z, b0.z, s);
    s = fmaf(a0.w, b0.w, s);
    s = fmaf(a1.x, b1.x, s);
    s = fmaf(a1.y, b1.y, s);
    s = fmaf(a1.z, b1.z, s);
    s = fmaf(a1.w, b1.w, s);
    return s;
}

__global__ __launch_bounds__(256) void sgns_f32(
    const int*   __restrict__ countp,
    const int*   __restrict__ shuffle,
    const int*   __restrict__ nodes_idx,
    const int*   __restrict__ neigh_idx,
    const int*   __restrict__ neg1,
    const int*   __restrict__ neg2,
    const int*   __restrict__ neg3,
    const float* __restrict__ node_W,
    const float* __restrict__ neigh_W,
    float*       __restrict__ acc)
{
    const int slot = blockIdx.x / BLOCKS_PER_TERM;
    const int blk  = blockIdx.x % BLOCKS_PER_TERM;
    const int wave = threadIdx.x >> 6;
    const int lane = threadIdx.x & 63;
    const int grp  = lane >> 4;
    const int lw   = lane & 15;
    const int count = countp[0];

    const int type = TMAP[slot][0];
    const int i    = TMAP[slot][1];
    const int j    = TMAP[slot][2];

    const int*   negBase;
    const float* negTable;
    if (type == 0)      { negTable = neigh_W + (size_t)i * N_ * D_; negBase = neg1 + (size_t)i * B_ * K_; }
    else if (type == 1) { negTable = node_W  + (size_t)j * N_ * D_; negBase = neg2 + (size_t)(j * V_ + i) * B_ * K_; }
    else                { negTable = neigh_W + (size_t)j * N_ * D_; negBase = neg3 + (size_t)(j * V_ + i) * B_ * K_; }

    float wsum = 0.f;
    const int rowbase = blk * ROWS_PER_BLOCK + wave * ROWS_PER_WAVE;

    for (int r = 0; r < ITERS; ++r) {
        const int b  = rowbase + r * GROUPS_PER_WAVE + grp;
        const int sh = shuffle[i * TOT_ + count + b];
        const int ns = nodes_idx[i * TOT_ + sh];

        const float* crow = node_W + ((size_t)i * N_ + ns) * (size_t)D_;
        float4 c0 = *(const float4*)(crow + lw * 4);
        float4 c1 = *(const float4*)(crow + 64 + lw * 4);

        const float* xrow;
        if (type == 0) {
            int gs = neigh_idx[i * TOT_ + sh];
            xrow = neigh_W + ((size_t)i * N_ + gs) * (size_t)D_;
        } else if (type == 1) {
            xrow = node_W + ((size_t)j * N_ + ns) * (size_t)D_;
        } else {
            int gs = neigh_idx[i * TOT_ + sh];
            xrow = neigh_W + ((size_t)j * N_ + gs) * (size_t)D_;
        }
        float4 x0 = *(const float4*)(xrow + lw * 4);
        float4 x1 = *(const float4*)(xrow + 64 + lw * 4);

        int myidx = (lw < K_) ? negBase[(size_t)b * K_ + lw] : 0;

        float rowacc = log_sigmoid(grp_sum16(dot8(c0, c1, x0, x1)));
#pragma unroll
        for (int k = 0; k < K_; ++k) {
            int nk = __shfl(myidx, (lane & 48) | k, 64);
            const float* nrow = negTable + (size_t)nk * (size_t)D_;
            float4 n0 = *(const float4*)(nrow + lw * 4);
            float4 n1 = *(const float4*)(nrow + 64 + lw * 4);
            rowacc += log_sigmoid(-grp_sum16(dot8(c0, c1, n0, n1)));
        }
        wsum += rowacc;
    }

    wsum += __shfl_xor(wsum, 16, 64);
    wsum += __shfl_xor(wsum, 32, 64);

    __shared__ float part[WAVES_PER_BLOCK];
    if (lane == 0) part[wave] = wsum;
    __syncthreads();
    if (threadIdx.x == 0) {
        float s = part[0] + part[1] + part[2] + part[3];
        atomicAdd(&acc[type], s);
    }
}

__global__ void finalize_kernel(const float* __restrict__ acc,
                                const float* __restrict__ hyp1,
                                const float* __restrict__ hyp2,
                                float* __restrict__ out)
{
    const float invB = 1.0f / (float)B_;
    float s1 = acc[0], s2 = acc[1], s3 = acc[2];
    out[0] = -(s1 * (invB / 9.0f) + hyp1[0] * s2 * (invB / 18.0f) + hyp2[0] * s3 * (invB / 18.0f));
}

extern "C" void kernel_launch(void* const* d_in, const int* in_sizes, int n_in,
                              void* d_out, int out_size, void* d_ws, size_t ws_size,
                              hipStream_t stream)
{
    const int*   countp    = (const int*)d_in[0];
    const int*   shuffle   = (const int*)d_in[1];
    const int*   nodes_idx = (const int*)d_in[2];
    const int*   neigh_idx = (const int*)d_in[3];
    const int*   neg1      = (const int*)d_in[4];
    const int*   neg2      = (const int*)d_in[5];
    const int*   neg3      = (const int*)d_in[6];
    const float* node_W    = (const float*)d_in[7];
    const float* neigh_W   = (const float*)d_in[8];
    const float* hyp1      = (const float*)d_in[9];
    const float* hyp2      = (const float*)d_in[10];

    float* acc = (float*)d_ws;
    dim3 block(256);

    if (ws_size >= WS_NEED) {
        unsigned* nodeT  = (unsigned*)((char*)d_ws + ACC_BYTES);
        unsigned* neighT = (unsigned*)((char*)d_ws + ACC_BYTES + FP8_TBL_BYTES);
        cvt_fp8_one<true ><<<CVT_BLOCKS, block, 0, stream>>>((const v4f*)node_W,  nodeT,  acc);
        cvt_fp8_one<false><<<CVT_BLOCKS, block, 0, stream>>>((const v4f*)neigh_W, neighT, acc);
        sgns_fp8<<<dim3(15 * BLOCKS_PER_TERM), block, 0, stream>>>(
            countp, shuffle, nodes_idx, neigh_idx, neg1, neg2, neg3,
            (const uint2*)nodeT, (const uint2*)neighT, acc);
    } else {
        (void)hipMemsetAsync(acc, 0, 3 * sizeof(float), stream);
        sgns_f32<<<dim3(15 * BLOCKS_PER_TERM), block, 0, stream>>>(
            countp, shuffle, nodes_idx, neigh_idx, neg1, neg2, neg3,
            node_W, neigh_W, acc);
    }

    finalize_kernel<<<1, 1, 0, stream>>>(acc, hyp1, hyp2, (float*)d_out);
}

// Round 15
// 258.807 us; speedup vs baseline: 1.0821x; 1.0821x over previous
//
#include <hip/hip_runtime.h>

#define V_   3
#define N_   200000
#define D_   128
#define B_   32768
#define K_   10
#define TOT_ 65536

constexpr int BLOCKS_PER_TERM = 512;
constexpr int ROWS_PER_BLOCK  = B_ / BLOCKS_PER_TERM;             // 64
constexpr int WAVES_PER_BLOCK = 4;                                // 256 threads
constexpr int ROWS_PER_WAVE   = ROWS_PER_BLOCK / WAVES_PER_BLOCK; // 16
constexpr int GROUPS_PER_WAVE = 4;                                // 16 lanes/row
constexpr int ITERS           = ROWS_PER_WAVE / GROUPS_PER_WAVE;  // 4

constexpr size_t TBL_ELEMS     = (size_t)V_ * N_ * D_;    // 76.8e6 per table
constexpr size_t FP8_TBL_BYTES = TBL_ELEMS;               // 76.8 MB per table
constexpr size_t ACC_BYTES     = 256;
constexpr size_t WS_NEED       = ACC_BYTES + 2 * FP8_TBL_BYTES;

// cvt geometry: single launch, block-granular table split. Per table:
// 9375 blocks * 256 thr * 8 items = 19,200,000 float4 exact. Grid = 18750.
constexpr int CVT_BLOCKS_PER_TBL = 9375;
constexpr int CVT_DEPTH          = 8;
constexpr int CVT_TILE           = 256 * CVT_DEPTH;

// Term schedule grouped by negative-sample table slice.
__device__ const int TMAP[15][3] = {
    {0, 0, 0}, {2, 1, 0}, {2, 2, 0},
    {0, 1, 1}, {2, 0, 1}, {2, 2, 1},
    {0, 2, 2}, {2, 0, 2}, {2, 1, 2},
    {1, 1, 0}, {1, 2, 0},
    {1, 0, 1}, {1, 2, 1},
    {1, 0, 2}, {1, 1, 2},
};

typedef float v2f __attribute__((ext_vector_type(2)));
typedef float v4f __attribute__((ext_vector_type(4)));

template <int CTRL>
__device__ __forceinline__ float dpp_add(float v) {
    int x = __builtin_amdgcn_update_dpp(0, __float_as_int(v), CTRL, 0xF, 0xF, true);
    return v + __int_as_float(x);
}

// 16-lane sum on the VALU pipe.
__device__ __forceinline__ float grp_sum16(float v) {
    v = dpp_add<0xB1>(v);
    v = dpp_add<0x4E>(v);
    v = dpp_add<0x124>(v);
    v = dpp_add<0x128>(v);
    return v;
}

__device__ __forceinline__ float log_sigmoid(float x) {
    float ax = fabsf(x);
    return fminf(x, 0.f) - __logf(1.f + __expf(-ax));
}

// ---------------- fp8 e4m3 helpers (HW cvt; selectors constant) ----------------
__device__ __forceinline__ unsigned cvt4_fp8(float a, float b, float c, float d) {
    int v = __builtin_amdgcn_cvt_pk_fp8_f32(a, b, 0, false);
    v = __builtin_amdgcn_cvt_pk_fp8_f32(c, d, v, true);
    return (unsigned)v;
}
template <bool HI>
__device__ __forceinline__ v2f upk2(unsigned v) {
    return __builtin_amdgcn_cvt_pk_f32_fp8((int)v, HI);
}

// Conversion, single launch. Block b < 9375 -> table A tile, else table B:
// each WAVE still touches exactly one read stream + one write stream (the
// property of the best r13 variant), but table A's tail overlaps B's head.
// NT loads (proven +20us r13 vs r14), 8-deep forced batch, tile-contiguous.
__global__ __launch_bounds__(256) void cvt_fp8_dual(
    const v4f* __restrict__ srcA, const v4f* __restrict__ srcB,
    unsigned* __restrict__ dstA, unsigned* __restrict__ dstB,
    float* __restrict__ acc)
{
    if (blockIdx.x == 0 && threadIdx.x < 8) acc[threadIdx.x] = 0.f;
    const bool tb = blockIdx.x >= CVT_BLOCKS_PER_TBL;
    const v4f* __restrict__ src = tb ? srcB : srcA;
    unsigned* __restrict__ dst  = tb ? dstB : dstA;
    const int bid = tb ? (blockIdx.x - CVT_BLOCKS_PER_TBL) : blockIdx.x;
    const size_t base = (size_t)bid * CVT_TILE + threadIdx.x;

    v4f v0, v1, v2, v3, v4, v5, v6, v7;
    v0 = __builtin_nontemporal_load(&src[base + 0 * 256]);
    v1 = __builtin_nontemporal_load(&src[base + 1 * 256]);
    v2 = __builtin_nontemporal_load(&src[base + 2 * 256]);
    v3 = __builtin_nontemporal_load(&src[base + 3 * 256]);
    v4 = __builtin_nontemporal_load(&src[base + 4 * 256]);
    v5 = __builtin_nontemporal_load(&src[base + 5 * 256]);
    v6 = __builtin_nontemporal_load(&src[base + 6 * 256]);
    v7 = __builtin_nontemporal_load(&src[base + 7 * 256]);
    __builtin_amdgcn_sched_barrier(0);

    dst[base + 0 * 256] = cvt4_fp8(v0.x, v0.y, v0.z, v0.w);
    dst[base + 1 * 256] = cvt4_fp8(v1.x, v1.y, v1.z, v1.w);
    dst[base + 2 * 256] = cvt4_fp8(v2.x, v2.y, v2.z, v2.w);
    dst[base + 3 * 256] = cvt4_fp8(v3.x, v3.y, v3.z, v3.w);
    dst[base + 4 * 256] = cvt4_fp8(v4.x, v4.y, v4.z, v4.w);
    dst[base + 5 * 256] = cvt4_fp8(v5.x, v5.y, v5.z, v5.w);
    dst[base + 6 * 256] = cvt4_fp8(v6.x, v6.y, v6.z, v6.w);
    dst[base + 7 * 256] = cvt4_fp8(v7.x, v7.y, v7.z, v7.w);
}

// dot of this lane's 8 fp8 elements against pre-decoded center (4 x v2f),
// using packed f32 math (v_pk_fma_f32).
__device__ __forceinline__ float dotv(v2f c0, v2f c1, v2f c2, v2f c3, uint2 n) {
    v2f a0 = c0 * upk2<false>(n.x);
    v2f a1 = c1 * upk2<true>(n.x);
    a0 += c2 * upk2<false>(n.y);
    a1 += c3 * upk2<true>(n.y);
    v2f a = a0 + a1;
    return a.x + a.y;
}

// ---------------- fp8 gather kernel (r13-proven, unchanged) ----------------
__global__ __launch_bounds__(256) void sgns_fp8(
    const int*   __restrict__ countp,
    const int*   __restrict__ shuffle,
    const int*   __restrict__ nodes_idx,
    const int*   __restrict__ neigh_idx,
    const int*   __restrict__ neg1,
    const int*   __restrict__ neg2,
    const int*   __restrict__ neg3,
    const uint2* __restrict__ nodeT,
    const uint2* __restrict__ neighT,
    float*       __restrict__ acc)
{
    const int slot = blockIdx.x / BLOCKS_PER_TERM;
    const int blk  = blockIdx.x % BLOCKS_PER_TERM;
    const int wave = threadIdx.x >> 6;
    const int lane = threadIdx.x & 63;
    const int grp  = lane >> 4;
    const int lw   = lane & 15;
    const int count = countp[0];

    const int type = TMAP[slot][0];
    const int i    = TMAP[slot][1];
    const int j    = TMAP[slot][2];

    const int*   negBase;
    const uint2* negTable;
    if (type == 0)      { negTable = neighT + (size_t)i * N_ * 16; negBase = neg1 + (size_t)i * B_ * K_; }
    else if (type == 1) { negTable = nodeT  + (size_t)j * N_ * 16; negBase = neg2 + (size_t)(j * V_ + i) * B_ * K_; }
    else                { negTable = neighT + (size_t)j * N_ * 16; negBase = neg3 + (size_t)(j * V_ + i) * B_ * K_; }

    float wsum = 0.f;
    const int rowbase = blk * ROWS_PER_BLOCK + wave * ROWS_PER_WAVE;

    for (int r = 0; r < ITERS; ++r) {
        const int b  = rowbase + r * GROUPS_PER_WAVE + grp;
        const int sh = shuffle[i * TOT_ + count + b];
        const int ns = nodes_idx[i * TOT_ + sh];

        uint2 c8 = nodeT[((size_t)i * N_ + ns) * 16 + lw];

        const uint2* xrow;
        if (type == 0) {
            int gs = neigh_idx[i * TOT_ + sh];
            xrow = neighT + ((size_t)i * N_ + gs) * 16;
        } else if (type == 1) {
            xrow = nodeT + ((size_t)j * N_ + ns) * 16;
        } else {
            int gs = neigh_idx[i * TOT_ + sh];
            xrow = neighT + ((size_t)j * N_ + gs) * 16;
        }
        uint2 x8 = xrow[lw];

        int myidx = (lw < K_) ? negBase[(size_t)b * K_ + lw] : 0;

        // Broadcast neg indices, then issue ALL 10 neg loads before reducing (MLP).
        uint2 nv[K_];
#pragma unroll
        for (int k = 0; k < K_; ++k) {
            int nk = __shfl(myidx, (lane & 48) | k, 64);
            nv[k] = negTable[(size_t)nk * 16 + lw];
        }

        v2f c0 = upk2<false>(c8.x), c1 = upk2<true>(c8.x);
        v2f c2 = upk2<false>(c8.y), c3 = upk2<true>(c8.y);

        float rowacc = log_sigmoid(grp_sum16(dotv(c0, c1, c2, c3, x8)));
#pragma unroll
        for (int k = 0; k < K_; ++k) {
            rowacc += log_sigmoid(-grp_sum16(dotv(c0, c1, c2, c3, nv[k])));
        }
        wsum += rowacc;
    }

    wsum += __shfl_xor(wsum, 16, 64);
    wsum += __shfl_xor(wsum, 32, 64);

    __shared__ float part[WAVES_PER_BLOCK];
    if (lane == 0) part[wave] = wsum;
    __syncthreads();
    if (threadIdx.x == 0) {
        float s = part[0] + part[1] + part[2] + part[3];
        atomicAdd(&acc[type], s);
    }
}

// ---------------- f32 fallback (proven round-3 kernel) ----------------
__device__ __forceinline__ float dot8(float4 a0, float4 a1, float4 b0, float4 b1) {
    float s = a0.x * b0.x;
    s = fmaf(a0.y, b0.y, s);
    s = fmaf(a0.z, b0.z, s);
    s = fmaf(a0.w, b0.w, s);
    s = fmaf(a1.x, b1.x, s);
    s = fmaf(a1.y, b1.y, s);
    s = fmaf(a1.z, b1.z, s);
    s = fmaf(a1.w, b1.w, s);
    return s;
}

__global__ __launch_bounds__(256) void sgns_f32(
    const int*   __restrict__ countp,
    const int*   __restrict__ shuffle,
    const int*   __restrict__ nodes_idx,
    const int*   __restrict__ neigh_idx,
    const int*   __restrict__ neg1,
    const int*   __restrict__ neg2,
    const int*   __restrict__ neg3,
    const float* __restrict__ node_W,
    const float* __restrict__ neigh_W,
    float*       __restrict__ acc)
{
    const int slot = blockIdx.x / BLOCKS_PER_TERM;
    const int blk  = blockIdx.x % BLOCKS_PER_TERM;
    const int wave = threadIdx.x >> 6;
    const int lane = threadIdx.x & 63;
    const int grp  = lane >> 4;
    const int lw   = lane & 15;
    const int count = countp[0];

    const int type = TMAP[slot][0];
    const int i    = TMAP[slot][1];
    const int j    = TMAP[slot][2];

    const int*   negBase;
    const float* negTable;
    if (type == 0)      { negTable = neigh_W + (size_t)i * N_ * D_; negBase = neg1 + (size_t)i * B_ * K_; }
    else if (type == 1) { negTable = node_W  + (size_t)j * N_ * D_; negBase = neg2 + (size_t)(j * V_ + i) * B_ * K_; }
    else                { negTable = neigh_W + (size_t)j * N_ * D_; negBase = neg3 + (size_t)(j * V_ + i) * B_ * K_; }

    float wsum = 0.f;
    const int rowbase = blk * ROWS_PER_BLOCK + wave * ROWS_PER_WAVE;

    for (int r = 0; r < ITERS; ++r) {
        const int b  = rowbase + r * GROUPS_PER_WAVE + grp;
        const int sh = shuffle[i * TOT_ + count + b];
        const int ns = nodes_idx[i * TOT_ + sh];

        const float* crow = node_W + ((size_t)i * N_ + ns) * (size_t)D_;
        float4 c0 = *(const float4*)(crow + lw * 4);
        float4 c1 = *(const float4*)(crow + 64 + lw * 4);

        const float* xrow;
        if (type == 0) {
            int gs = neigh_idx[i * TOT_ + sh];
            xrow = neigh_W + ((size_t)i * N_ + gs) * (size_t)D_;
        } else if (type == 1) {
            xrow = node_W + ((size_t)j * N_ + ns) * (size_t)D_;
        } else {
            int gs = neigh_idx[i * TOT_ + sh];
            xrow = neigh_W + ((size_t)j * N_ + gs) * (size_t)D_;
        }
        float4 x0 = *(const float4*)(xrow + lw * 4);
        float4 x1 = *(const float4*)(xrow + 64 + lw * 4);

        int myidx = (lw < K_) ? negBase[(size_t)b * K_ + lw] : 0;

        float rowacc = log_sigmoid(grp_sum16(dot8(c0, c1, x0, x1)));
#pragma unroll
        for (int k = 0; k < K_; ++k) {
            int nk = __shfl(myidx, (lane & 48) | k, 64);
            const float* nrow = negTable + (size_t)nk * (size_t)D_;
            float4 n0 = *(const float4*)(nrow + lw * 4);
            float4 n1 = *(const float4*)(nrow + 64 + lw * 4);
            rowacc += log_sigmoid(-grp_sum16(dot8(c0, c1, n0, n1)));
        }
        wsum += rowacc;
    }

    wsum += __shfl_xor(wsum, 16, 64);
    wsum += __shfl_xor(wsum, 32, 64);

    __shared__ float part[WAVES_PER_BLOCK];
    if (lane == 0) part[wave] = wsum;
    __syncthreads();
    if (threadIdx.x == 0) {
        float s = part[0] + part[1] + part[2] + part[3];
        atomicAdd(&acc[type], s);
    }
}

__global__ void finalize_kernel(const float* __restrict__ acc,
                                const float* __restrict__ hyp1,
                                const float* __restrict__ hyp2,
                                float* __restrict__ out)
{
    const float invB = 1.0f / (float)B_;
    float s1 = acc[0], s2 = acc[1], s3 = acc[2];
    out[0] = -(s1 * (invB / 9.0f) + hyp1[0] * s2 * (invB / 18.0f) + hyp2[0] * s3 * (invB / 18.0f));
}

extern "C" void kernel_launch(void* const* d_in, const int* in_sizes, int n_in,
                              void* d_out, int out_size, void* d_ws, size_t ws_size,
                              hipStream_t stream)
{
    const int*   countp    = (const int*)d_in[0];
    const int*   shuffle   = (const int*)d_in[1];
    const int*   nodes_idx = (const int*)d_in[2];
    const int*   neigh_idx = (const int*)d_in[3];
    const int*   neg1      = (const int*)d_in[4];
    const int*   neg2      = (const int*)d_in[5];
    const int*   neg3      = (const int*)d_in[6];
    const float* node_W    = (const float*)d_in[7];
    const float* neigh_W   = (const float*)d_in[8];
    const float* hyp1      = (const float*)d_in[9];
    const float* hyp2      = (const float*)d_in[10];

    float* acc = (float*)d_ws;
    dim3 block(256);

    if (ws_size >= WS_NEED) {
        unsigned* nodeT  = (unsigned*)((char*)d_ws + ACC_BYTES);
        unsigned* neighT = (unsigned*)((char*)d_ws + ACC_BYTES + FP8_TBL_BYTES);
        cvt_fp8_dual<<<2 * CVT_BLOCKS_PER_TBL, block, 0, stream>>>(
            (const v4f*)node_W, (const v4f*)neigh_W, nodeT, neighT, acc);
        sgns_fp8<<<dim3(15 * BLOCKS_PER_TERM), block, 0, stream>>>(
            countp, shuffle, nodes_idx, neigh_idx, neg1, neg2, neg3,
            (const uint2*)nodeT, (const uint2*)neighT, acc);
    } else {
        (void)hipMemsetAsync(acc, 0, 3 * sizeof(float), stream);
        sgns_f32<<<dim3(15 * BLOCKS_PER_TERM), block, 0, stream>>>(
            countp, shuffle, nodes_idx, neigh_idx, neg1, neg2, neg3,
            node_W, neigh_W, acc);
    }

    finalize_kernel<<<1, 1, 0, stream>>>(acc, hyp1, hyp2, (float*)d_out);
}